// Round 13
// baseline (217.692 us; speedup 1.0000x reference)
//
#include <hip/hip_runtime.h>
#include <hip/hip_bf16.h>

// Problem dims: x[b=8, c=64, h=64, w=64, t=12] fp32
// x float offsets: b*3145728 + c*49152 + h*768 + w*12 + t
//
// Scratch inside d_out (floats), consumed before k_out overwrites d_out:
//   [0,1600)           : Weff[c*25 + tap],  tap = dh*5+dw
//   [4096, 4096+9.83M) : y[tap][m*12+t], m = (b*64+h)*64+w   (25 planes, 39.3 MB)
#define WEFF_OFF 0
#define Y_OFF    4096
#define Y_PLANE  393216   // floats per tap plane
// d_ws: p[m*12 + t]  (1.57 MB)

// ---------------------------------------------------------------------------
// K1: fold 1x1-conv (key half of w1) into the 5x5 conv weights.
__global__ __launch_bounds__(256) void k_prep(const float* __restrict__ w1,
                                              const float* __restrict__ w2,
                                              float* __restrict__ weff) {
    int idx = blockIdx.x * 256 + threadIdx.x;
    if (idx >= 64 * 25) return;
    int cp = idx / 25, tap = idx % 25;
    float s = 0.f;
    for (int c = 0; c < 64; ++c)
        s = fmaf(w2[(64 + c) * 25 + tap], w1[(64 + c) * 64 + cp], s);
    weff[cp * 25 + tap] = s;
}

// ---------------------------------------------------------------------------
// K2a (k_tap v6): per-tap c-contraction satisfying ALL four conditions that
// no prior variant met together:
//  (a) 1536x256 = 24 waves/CU (6/SIMD)
//  (b) 8 independent scalar x-loads per batch, double-buffered vbuf[2][8]
//      (static parity idx), PINNED above the FMA region by sched_barrier(0)
//  (c) weights wave-uniform (s_load, compiler-prefetchable), none in the
//      vmcnt chain
//  (d) scalar acc[25] -> ~50 VGPR, no spill
// Per-block channel-phase rotation (cbp=(cb+bid)&7) decorrelates the 192KB
// c-stride walk across blocks (L2-set / channel camping insurance).
__global__ __launch_bounds__(256) void k_tap(const float* __restrict__ x,
                                             const float* __restrict__ weff,
                                             float* __restrict__ y) {
    const int gid = blockIdx.x * 256 + threadIdx.x;   // 0..393215 = m*12+t
    const int m   = gid / 12;
    const int t   = gid - m * 12;
    const int b   = m >> 12;

    // per-thread base: consecutive gid -> consecutive addresses (256B/wave)
    const float* xp = x + (size_t)b * 3145728 + (size_t)(m & 4095) * 12 + t;

    float acc[25];
#pragma unroll
    for (int k = 0; k < 25; ++k) acc[k] = 0.f;

    const int ph = blockIdx.x & 7;    // channel-phase per block

    float vbuf[2][8];
    {
        const float* xc = xp + (size_t)ph * 8 * 49152;
#pragma unroll
        for (int j = 0; j < 8; ++j)
            vbuf[0][j] = xc[(size_t)j * 49152];
    }
    __builtin_amdgcn_sched_barrier(0);   // pin prologue loads

#pragma unroll
    for (int cb = 0; cb < 8; ++cb) {
        const int cur = cb & 1;
        const int nxt = cur ^ 1;
        const int cbp = (cb + ph) & 7;

        if (cb < 7) {
            const int cbn = (cb + 1 + ph) & 7;
            const float* xc = xp + (size_t)cbn * 8 * 49152;
#pragma unroll
            for (int j = 0; j < 8; ++j)
                vbuf[nxt][j] = xc[(size_t)j * 49152];
        }
        __builtin_amdgcn_sched_barrier(0);   // loads above, FMA below

#pragma unroll
        for (int j = 0; j < 8; ++j) {
            const float* wg = weff + (cbp * 8 + j) * 25;   // wave-uniform
            const float v = vbuf[cur][j];
#pragma unroll
            for (int k = 0; k < 25; ++k)
                acc[k] = fmaf(wg[k], v, acc[k]);
        }
    }

#pragma unroll
    for (int k = 0; k < 25; ++k)
        y[(size_t)k * Y_PLANE + gid] = acc[k];
}

// ---------------------------------------------------------------------------
// K2b (k_gather): A_k[m,t] = sum_taps y[tap][shifted m, t] (OOB skipped ==
// zero-pad), softmax over t, write p. Lane-quad per m: q=0..2 own t-quads,
// lane 3 duplicates lane 2. 131,072 threads = 8 waves/CU; y is L3-resident.
__global__ __launch_bounds__(256) void k_gather(const float* __restrict__ y,
                                                float* __restrict__ p) {
    const int tid  = threadIdx.x;
    const int m    = blockIdx.x * 64 + (tid >> 2);   // 0..32767
    const int q    = tid & 3;
    const int qq   = (q == 3) ? 2 : q;               // lane3 mirrors lane2
    const int w    = m & 63;
    const int h    = (m >> 6) & 63;
    const int b    = m >> 12;

    float4 a; a.x = 0.f; a.y = 0.f; a.z = 0.f; a.w = 0.f;

#pragma unroll
    for (int dh = 0; dh < 5; ++dh) {
        const int hh = h + dh - 2;
        if ((unsigned)hh >= 64u) continue;           // block-uniform skip
        const int rowb = (b * 64 + hh) * 64;
#pragma unroll
        for (int dw = 0; dw < 5; ++dw) {
            const int ww = w + dw - 2;
            if ((unsigned)ww >= 64u) continue;       // edge lanes only
            const float* yp = y + (size_t)(dh * 5 + dw) * Y_PLANE
                                + (size_t)(rowb + ww) * 12 + qq * 4;
            float4 v = *(const float4*)(yp);
            a.x += v.x; a.y += v.y; a.z += v.z; a.w += v.w;
        }
    }

    // softmax over 12 t across lanes q=0..2 of the quad
    float mx = fmaxf(fmaxf(a.x, a.y), fmaxf(a.z, a.w));
    mx = fmaxf(mx, __shfl_xor(mx, 1, 4));
    mx = fmaxf(mx, __shfl_xor(mx, 2, 4));   // lane3 dup is idempotent for max

    float e0 = __expf(a.x - mx), e1 = __expf(a.y - mx);
    float e2 = __expf(a.z - mx), e3 = __expf(a.w - mx);
    const float s4 = e0 + e1 + e2 + e3;
    const float s0 = __shfl(s4, 0, 4);
    const float s1 = __shfl(s4, 1, 4);
    const float s2 = __shfl(s4, 2, 4);
    const float inv = 1.f / (s0 + s1 + s2);

    if (q < 3) {
        float4 o; o.x = e0 * inv; o.y = e1 * inv; o.z = e2 * inv; o.w = e3 * inv;
        *(float4*)(p + (size_t)m * 12 + q * 4) = o;
    }
}

// ---------------------------------------------------------------------------
// K4: out[b,c,h,w,s] = W1v · (sum_t p_t * x[:,t]) + b1v, broadcast over s.
// One block per (b,h): 512 threads = 64 w-lanes * 8 channel-groups.
__global__ __launch_bounds__(512) void k_out(const float* __restrict__ x,
                                             const float* __restrict__ w1,
                                             const float* __restrict__ b1,
                                             const float* __restrict__ p,
                                             float* __restrict__ out) {
    __shared__ float lds[64 * 65];   // [w][c], padded -> conflict-free

    const int b  = blockIdx.x >> 6;
    const int h  = blockIdx.x & 63;
    const int w  = threadIdx.x & 63;
    const int cg = threadIdx.x >> 6;     // 0..7

    const float* pp = p + (size_t)((b * 64 + h) * 64 + w) * 12;
    float pv[12];
    {
        float4 t0 = *(const float4*)(pp);
        float4 t1 = *(const float4*)(pp + 4);
        float4 t2 = *(const float4*)(pp + 8);
        pv[0] = t0.x; pv[1] = t0.y; pv[2]  = t0.z; pv[3]  = t0.w;
        pv[4] = t1.x; pv[5] = t1.y; pv[6]  = t1.z; pv[7]  = t1.w;
        pv[8] = t2.x; pv[9] = t2.y; pv[10] = t2.z; pv[11] = t2.w;
    }

    const float* xb0 = x + ((size_t)(b * 64 + cg * 8) * 64 + h) * 768 + w * 12;
#pragma unroll
    for (int j = 0; j < 8; ++j) {
        const float* xp = xb0 + (size_t)j * 49152;
        float4 u0 = *(const float4*)(xp);
        float4 u1 = *(const float4*)(xp + 4);
        float4 u2 = *(const float4*)(xp + 8);
        float s = 0.f;
        s = fmaf(pv[0], u0.x, s);  s = fmaf(pv[1], u0.y, s);
        s = fmaf(pv[2], u0.z, s);  s = fmaf(pv[3], u0.w, s);
        s = fmaf(pv[4], u1.x, s);  s = fmaf(pv[5], u1.y, s);
        s = fmaf(pv[6], u1.z, s);  s = fmaf(pv[7], u1.w, s);
        s = fmaf(pv[8], u2.x, s);  s = fmaf(pv[9], u2.y, s);
        s = fmaf(pv[10], u2.z, s); s = fmaf(pv[11], u2.w, s);
        lds[w * 65 + cg * 8 + j] = s;
    }
    __syncthreads();

    const float* w1v = w1 + 128 * 64 + cg * 8 * 64;
    float acc[8];
#pragma unroll
    for (int j = 0; j < 8; ++j) acc[j] = b1[128 + cg * 8 + j];
    for (int c2 = 0; c2 < 64; ++c2) {
        const float xv = lds[w * 65 + c2];
#pragma unroll
        for (int j = 0; j < 8; ++j)
            acc[j] = fmaf(w1v[j * 64 + c2], xv, acc[j]);
    }

#pragma unroll
    for (int j = 0; j < 8; ++j) {
        const int co = cg * 8 + j;
        float4 f; f.x = acc[j]; f.y = acc[j]; f.z = acc[j]; f.w = acc[j];
        float* op = out + ((size_t)(b * 64 + co) * 4096 + h * 64 + w) * 12;
        *(float4*)(op)     = f;
        *(float4*)(op + 4) = f;
        *(float4*)(op + 8) = f;
    }
}

// ---------------------------------------------------------------------------
extern "C" void kernel_launch(void* const* d_in, const int* in_sizes, int n_in,
                              void* d_out, int out_size, void* d_ws, size_t ws_size,
                              hipStream_t stream) {
    const float* x  = (const float*)d_in[0];
    const float* w1 = (const float*)d_in[1];
    const float* b1 = (const float*)d_in[2];
    const float* w2 = (const float*)d_in[3];
    // d_in[4] = b2: constant across the softmax axis -> cancels, unused.

    float* outp = (float*)d_out;
    float* weff = outp + WEFF_OFF;
    float* y    = outp + Y_OFF;      // 39.3 MB tap planes (scratch in d_out)
    float* p    = (float*)d_ws;      // 1.57 MB

    hipLaunchKernelGGL(k_prep,   dim3(7),    dim3(256), 0, stream, w1, w2, weff);
    hipLaunchKernelGGL(k_tap,    dim3(1536), dim3(256), 0, stream, x, weff, y);
    hipLaunchKernelGGL(k_gather, dim3(512),  dim3(256), 0, stream, y, p);
    hipLaunchKernelGGL(k_out,    dim3(512),  dim3(512), 0, stream, x, w1, b1, p, outp);
}

// Round 14
// 143.599 us; speedup vs baseline: 1.5160x; 1.5160x over previous
//
#include <hip/hip_runtime.h>
#include <hip/hip_bf16.h>

// Problem dims: x[b=8, c=64, h=64, w=64, t=12] fp32
// x float offsets: b*3145728 + c*49152 + h*768 + w*12 + t
//
// Scratch inside d_out (floats), consumed before k_out overwrites d_out:
//   [0,2048)           : weffT[tap*64 + c]   (transposed folded weights)
//   [4096, 4096+9.83M) : y[tap][m*12+t], m = (b*64+h)*64+w   (25 planes, 39.3 MB)
#define WEFFT_OFF 0
#define Y_OFF     4096
#define Y_PLANE   393216   // floats per tap plane
// d_ws: p[m*12 + t]  (1.57 MB)

// ---------------------------------------------------------------------------
// K1: fold 1x1-conv (key half of w1) into 5x5 weights, TRANSPOSED layout:
// weffT[tap*64 + c] = sum_cc w2[0, 64+cc, tap] * w1[64+cc, c]
__global__ __launch_bounds__(256) void k_prep(const float* __restrict__ w1,
                                              const float* __restrict__ w2,
                                              float* __restrict__ weffT) {
    int idx = blockIdx.x * 256 + threadIdx.x;
    if (idx >= 25 * 64) return;
    int tap = idx >> 6, c = idx & 63;
    float s = 0.f;
    for (int cc = 0; cc < 64; ++cc)
        s = fmaf(w2[(64 + cc) * 25 + tap], w1[(64 + cc) * 64 + c], s);
    weffT[tap * 64 + c] = s;
}

// ---------------------------------------------------------------------------
// K2a (k_tap v7): structurally cloned from k_out (the only measured-fast
// x-reader). Block = (b,h,tg): 512 thr = 64 w x 8 cg.
// Phase 1 = k_out's exact load shape: 8 INDEPENDENT float4 loads per thread
// (channels cg*8..cg*8+7, 48B columns), straight to LDS [c][w] (16B/lane
// contiguous both sides, conflict-free). NO weights, NO FMA in the chain.
// Phase 2: c-contraction from LDS (canonical ds_read_b128) with wave-uniform
// s_load weights (k_out phase-2 pattern). Wave cg computes taps 3cg..3cg+2
// (+ tap 24 on cg7). Static-named accumulators (no runtime indexing).
__global__ __launch_bounds__(512) void k_tap(const float* __restrict__ x,
                                             const float* __restrict__ weffT,
                                             float* __restrict__ y) {
    __shared__ float4 xl[64 * 64];   // [c][w], 64 KB

    const int bid = blockIdx.x;      // 1536 = (b,h,tg)
    const int tg  = bid % 3;
    const int h   = (bid / 3) & 63;
    const int b   = bid / 192;
    const int w   = threadIdx.x & 63;
    const int cg  = threadIdx.x >> 6;    // wave id 0..7

    // phase 1: pure streaming burst -> LDS
    const float* xb = x + (size_t)b * 3145728 + (size_t)(cg * 8) * 49152
                        + h * 768 + w * 12 + tg * 4;
    float4 v[8];
#pragma unroll
    for (int j = 0; j < 8; ++j)
        v[j] = *(const float4*)(xb + (size_t)j * 49152);
#pragma unroll
    for (int j = 0; j < 8; ++j)
        xl[(cg * 8 + j) * 64 + w] = v[j];
    __syncthreads();

    // phase 2: taps t0..t2 (+24 for cg7), weights wave-uniform -> s_load
    const int t0 = cg * 3;
    const float* w0 = weffT + (t0 + 0) * 64;
    const float* w1p = weffT + (t0 + 1) * 64;
    const float* w2p = weffT + (t0 + 2) * 64;
    const float* w3p = weffT + 24 * 64;       // only used by cg7

    float4 a0, a1, a2, a3;
    a0.x=0.f;a0.y=0.f;a0.z=0.f;a0.w=0.f; a1=a0; a2=a0; a3=a0;

#pragma unroll 4
    for (int c = 0; c < 64; ++c) {
        const float4 xv = xl[c * 64 + w];
        const float g0 = w0[c], g1 = w1p[c], g2 = w2p[c];
        a0.x = fmaf(g0, xv.x, a0.x); a0.y = fmaf(g0, xv.y, a0.y);
        a0.z = fmaf(g0, xv.z, a0.z); a0.w = fmaf(g0, xv.w, a0.w);
        a1.x = fmaf(g1, xv.x, a1.x); a1.y = fmaf(g1, xv.y, a1.y);
        a1.z = fmaf(g1, xv.z, a1.z); a1.w = fmaf(g1, xv.w, a1.w);
        a2.x = fmaf(g2, xv.x, a2.x); a2.y = fmaf(g2, xv.y, a2.y);
        a2.z = fmaf(g2, xv.z, a2.z); a2.w = fmaf(g2, xv.w, a2.w);
        if (cg == 7) {                         // wave-uniform branch
            const float g3 = w3p[c];
            a3.x = fmaf(g3, xv.x, a3.x); a3.y = fmaf(g3, xv.y, a3.y);
            a3.z = fmaf(g3, xv.z, a3.z); a3.w = fmaf(g3, xv.w, a3.w);
        }
    }

    const size_t mbase = (size_t)((b * 64 + h) * 64 + w) * 12 + tg * 4;
    *(float4*)(y + (size_t)(t0 + 0) * Y_PLANE + mbase) = a0;
    *(float4*)(y + (size_t)(t0 + 1) * Y_PLANE + mbase) = a1;
    *(float4*)(y + (size_t)(t0 + 2) * Y_PLANE + mbase) = a2;
    if (cg == 7)
        *(float4*)(y + (size_t)24 * Y_PLANE + mbase) = a3;
}

// ---------------------------------------------------------------------------
// K2b (k_gather): A_k[m,t] = sum_taps y[tap][shifted m, t] (OOB skipped ==
// zero-pad), softmax over t, write p. Lane-quad per m; proven ~8 us.
__global__ __launch_bounds__(256) void k_gather(const float* __restrict__ y,
                                                float* __restrict__ p) {
    const int tid  = threadIdx.x;
    const int m    = blockIdx.x * 64 + (tid >> 2);   // 0..32767
    const int q    = tid & 3;
    const int qq   = (q == 3) ? 2 : q;               // lane3 mirrors lane2
    const int w    = m & 63;
    const int h    = (m >> 6) & 63;
    const int b    = m >> 12;

    float4 a; a.x = 0.f; a.y = 0.f; a.z = 0.f; a.w = 0.f;

#pragma unroll
    for (int dh = 0; dh < 5; ++dh) {
        const int hh = h + dh - 2;
        if ((unsigned)hh >= 64u) continue;
        const int rowb = (b * 64 + hh) * 64;
#pragma unroll
        for (int dw = 0; dw < 5; ++dw) {
            const int ww = w + dw - 2;
            if ((unsigned)ww >= 64u) continue;
            const float* yp = y + (size_t)(dh * 5 + dw) * Y_PLANE
                                + (size_t)(rowb + ww) * 12 + qq * 4;
            float4 v = *(const float4*)(yp);
            a.x += v.x; a.y += v.y; a.z += v.z; a.w += v.w;
        }
    }

    float mx = fmaxf(fmaxf(a.x, a.y), fmaxf(a.z, a.w));
    mx = fmaxf(mx, __shfl_xor(mx, 1, 4));
    mx = fmaxf(mx, __shfl_xor(mx, 2, 4));

    float e0 = __expf(a.x - mx), e1 = __expf(a.y - mx);
    float e2 = __expf(a.z - mx), e3 = __expf(a.w - mx);
    const float s4 = e0 + e1 + e2 + e3;
    const float s0 = __shfl(s4, 0, 4);
    const float s1 = __shfl(s4, 1, 4);
    const float s2 = __shfl(s4, 2, 4);
    const float inv = 1.f / (s0 + s1 + s2);

    if (q < 3) {
        float4 o; o.x = e0 * inv; o.y = e1 * inv; o.z = e2 * inv; o.w = e3 * inv;
        *(float4*)(p + (size_t)m * 12 + q * 4) = o;
    }
}

// ---------------------------------------------------------------------------
// K4: out[b,c,h,w,s] = W1v · (sum_t p_t * x[:,t]) + b1v, broadcast over s.
// One block per (b,h): 512 threads = 64 w-lanes * 8 channel-groups.
__global__ __launch_bounds__(512) void k_out(const float* __restrict__ x,
                                             const float* __restrict__ w1,
                                             const float* __restrict__ b1,
                                             const float* __restrict__ p,
                                             float* __restrict__ out) {
    __shared__ float lds[64 * 65];   // [w][c], padded -> conflict-free

    const int b  = blockIdx.x >> 6;
    const int h  = blockIdx.x & 63;
    const int w  = threadIdx.x & 63;
    const int cg = threadIdx.x >> 6;     // 0..7

    const float* pp = p + (size_t)((b * 64 + h) * 64 + w) * 12;
    float pv[12];
    {
        float4 t0 = *(const float4*)(pp);
        float4 t1 = *(const float4*)(pp + 4);
        float4 t2 = *(const float4*)(pp + 8);
        pv[0] = t0.x; pv[1] = t0.y; pv[2]  = t0.z; pv[3]  = t0.w;
        pv[4] = t1.x; pv[5] = t1.y; pv[6]  = t1.z; pv[7]  = t1.w;
        pv[8] = t2.x; pv[9] = t2.y; pv[10] = t2.z; pv[11] = t2.w;
    }

    const float* xb0 = x + ((size_t)(b * 64 + cg * 8) * 64 + h) * 768 + w * 12;
#pragma unroll
    for (int j = 0; j < 8; ++j) {
        const float* xp = xb0 + (size_t)j * 49152;
        float4 u0 = *(const float4*)(xp);
        float4 u1 = *(const float4*)(xp + 4);
        float4 u2 = *(const float4*)(xp + 8);
        float s = 0.f;
        s = fmaf(pv[0], u0.x, s);  s = fmaf(pv[1], u0.y, s);
        s = fmaf(pv[2], u0.z, s);  s = fmaf(pv[3], u0.w, s);
        s = fmaf(pv[4], u1.x, s);  s = fmaf(pv[5], u1.y, s);
        s = fmaf(pv[6], u1.z, s);  s = fmaf(pv[7], u1.w, s);
        s = fmaf(pv[8], u2.x, s);  s = fmaf(pv[9], u2.y, s);
        s = fmaf(pv[10], u2.z, s); s = fmaf(pv[11], u2.w, s);
        lds[w * 65 + cg * 8 + j] = s;
    }
    __syncthreads();

    const float* w1v = w1 + 128 * 64 + cg * 8 * 64;
    float acc[8];
#pragma unroll
    for (int j = 0; j < 8; ++j) acc[j] = b1[128 + cg * 8 + j];
    for (int c2 = 0; c2 < 64; ++c2) {
        const float xv = lds[w * 65 + c2];
#pragma unroll
        for (int j = 0; j < 8; ++j)
            acc[j] = fmaf(w1v[j * 64 + c2], xv, acc[j]);
    }

#pragma unroll
    for (int j = 0; j < 8; ++j) {
        const int co = cg * 8 + j;
        float4 f; f.x = acc[j]; f.y = acc[j]; f.z = acc[j]; f.w = acc[j];
        float* op = out + ((size_t)(b * 64 + co) * 4096 + h * 64 + w) * 12;
        *(float4*)(op)     = f;
        *(float4*)(op + 4) = f;
        *(float4*)(op + 8) = f;
    }
}

// ---------------------------------------------------------------------------
extern "C" void kernel_launch(void* const* d_in, const int* in_sizes, int n_in,
                              void* d_out, int out_size, void* d_ws, size_t ws_size,
                              hipStream_t stream) {
    const float* x  = (const float*)d_in[0];
    const float* w1 = (const float*)d_in[1];
    const float* b1 = (const float*)d_in[2];
    const float* w2 = (const float*)d_in[3];
    // d_in[4] = b2: constant across the softmax axis -> cancels, unused.

    float* outp  = (float*)d_out;
    float* weffT = outp + WEFFT_OFF;
    float* y     = outp + Y_OFF;     // 39.3 MB tap planes (scratch in d_out)
    float* p     = (float*)d_ws;     // 1.57 MB

    hipLaunchKernelGGL(k_prep,   dim3(7),    dim3(256), 0, stream, w1, w2, weffT);
    hipLaunchKernelGGL(k_tap,    dim3(1536), dim3(512), 0, stream, x, weffT, y);
    hipLaunchKernelGGL(k_gather, dim3(512),  dim3(256), 0, stream, y, p);
    hipLaunchKernelGGL(k_out,    dim3(512),  dim3(512), 0, stream, x, w1, b1, p, outp);
}

// Round 15
// 99.190 us; speedup vs baseline: 2.1947x; 1.4477x over previous
//
#include <hip/hip_runtime.h>
#include <hip/hip_bf16.h>

// Problem dims: x[b=8, c=64, h=64, w=64, t=12] fp32
// x float offsets: b*3145728 + c*49152 + h*768 + w*12 + t
//
// Scratch inside d_out (floats), consumed before k_out overwrites d_out:
//   [0,1600)           : Weff fallback slot (only if ws too small)
//   [4096, 4096+9.83M) : y[tap][m*12+t], m = (b*64+h)*64+w   (25 planes, 39.3 MB)
#define WEFF_OFF 0
#define Y_OFF    4096
#define Y_PLANE  393216   // floats per tap plane
// d_ws: p[m*12+t] (1.57 MB) + weff copy at float offset 393216 (6.4 KB)
#define WS_WEFF_OFF 393216

// ---------------------------------------------------------------------------
// K1: fold 1x1-conv (key half of w1) into the 5x5 conv weights.
// Writes to wdst (normally inside d_ws -> physically disjoint from y, so
// k_tap's uniform weight loads carry clean no-alias provenance).
__global__ __launch_bounds__(256) void k_prep(const float* __restrict__ w1,
                                              const float* __restrict__ w2,
                                              float* __restrict__ wdst) {
    int idx = blockIdx.x * 256 + threadIdx.x;
    if (idx >= 64 * 25) return;
    int cp = idx / 25, tap = idx % 25;
    float s = 0.f;
    for (int c = 0; c < 64; ++c)
        s = fmaf(w2[(64 + c) * 25 + tap], w1[(64 + c) * 64 + cp], s);
    wdst[cp * 25 + tap] = s;
}

// ---------------------------------------------------------------------------
// K2a (k_tap, R7-proven config): per-tap channel contraction.
// Thread per (m,t): 1536x256 = 24 waves/CU; scalar coalesced x loads
// (256B/wave), acc[25] scalar (~50 VGPR). x read exactly once chip-wide.
// Weights read wave-uniform from weff (now in d_ws: disjoint provenance).
__global__ __launch_bounds__(256) void k_tap(const float* __restrict__ x,
                                             const float* __restrict__ weff,
                                             float* __restrict__ y) {
    const int gid = blockIdx.x * 256 + threadIdx.x;   // 0..393215 = m*12+t
    const int m   = gid / 12;
    const int t   = gid - m * 12;
    const int w   = m & 63;
    const int h   = (m >> 6) & 63;
    const int b   = m >> 12;

    const float* xp = x + (size_t)b * 3145728 + h * 768 + w * 12 + t;

    float acc[25];
#pragma unroll
    for (int k = 0; k < 25; ++k) acc[k] = 0.f;

    for (int c = 0; c < 64; ++c) {
        const float v = xp[(size_t)c * 49152];
        const float* wg = weff + c * 25;   // wave-uniform -> scalar loads
#pragma unroll
        for (int k = 0; k < 25; ++k)
            acc[k] = fmaf(wg[k], v, acc[k]);
    }

#pragma unroll
    for (int k = 0; k < 25; ++k)
        y[(size_t)k * Y_PLANE + gid] = acc[k];
}

// ---------------------------------------------------------------------------
// K2b (k_gather): A_k[m,t] = sum_taps y[tap][shifted m, t] (OOB skipped ==
// zero-pad), softmax over t, write p. Lane-quad per m; proven ~8 us.
__global__ __launch_bounds__(256) void k_gather(const float* __restrict__ y,
                                                float* __restrict__ p) {
    const int tid  = threadIdx.x;
    const int m    = blockIdx.x * 64 + (tid >> 2);   // 0..32767
    const int q    = tid & 3;
    const int qq   = (q == 3) ? 2 : q;               // lane3 mirrors lane2
    const int w    = m & 63;
    const int h    = (m >> 6) & 63;
    const int b    = m >> 12;

    float4 a; a.x = 0.f; a.y = 0.f; a.z = 0.f; a.w = 0.f;

#pragma unroll
    for (int dh = 0; dh < 5; ++dh) {
        const int hh = h + dh - 2;
        if ((unsigned)hh >= 64u) continue;           // block-uniform skip
        const int rowb = (b * 64 + hh) * 64;
#pragma unroll
        for (int dw = 0; dw < 5; ++dw) {
            const int ww = w + dw - 2;
            if ((unsigned)ww >= 64u) continue;       // edge lanes only
            const float* yp = y + (size_t)(dh * 5 + dw) * Y_PLANE
                                + (size_t)(rowb + ww) * 12 + qq * 4;
            float4 v = *(const float4*)(yp);
            a.x += v.x; a.y += v.y; a.z += v.z; a.w += v.w;
        }
    }

    float mx = fmaxf(fmaxf(a.x, a.y), fmaxf(a.z, a.w));
    mx = fmaxf(mx, __shfl_xor(mx, 1, 4));
    mx = fmaxf(mx, __shfl_xor(mx, 2, 4));   // lane3 dup is idempotent for max

    float e0 = __expf(a.x - mx), e1 = __expf(a.y - mx);
    float e2 = __expf(a.z - mx), e3 = __expf(a.w - mx);
    const float s4 = e0 + e1 + e2 + e3;
    const float s0 = __shfl(s4, 0, 4);
    const float s1 = __shfl(s4, 1, 4);
    const float s2 = __shfl(s4, 2, 4);
    const float inv = 1.f / (s0 + s1 + s2);

    if (q < 3) {
        float4 o; o.x = e0 * inv; o.y = e1 * inv; o.z = e2 * inv; o.w = e3 * inv;
        *(float4*)(p + (size_t)m * 12 + q * 4) = o;
    }
}

// ---------------------------------------------------------------------------
// K4: out[b,c,h,w,s] = W1v · (sum_t p_t * x[:,t]) + b1v, broadcast over s.
// One block per (b,h): 512 threads = 64 w-lanes * 8 channel-groups.
// Proven ~34 us (at its 200MB roofline).
__global__ __launch_bounds__(512) void k_out(const float* __restrict__ x,
                                             const float* __restrict__ w1,
                                             const float* __restrict__ b1,
                                             const float* __restrict__ p,
                                             float* __restrict__ out) {
    __shared__ float lds[64 * 65];   // [w][c], padded -> conflict-free

    const int b  = blockIdx.x >> 6;
    const int h  = blockIdx.x & 63;
    const int w  = threadIdx.x & 63;
    const int cg = threadIdx.x >> 6;     // 0..7

    const float* pp = p + (size_t)((b * 64 + h) * 64 + w) * 12;
    float pv[12];
    {
        float4 t0 = *(const float4*)(pp);
        float4 t1 = *(const float4*)(pp + 4);
        float4 t2 = *(const float4*)(pp + 8);
        pv[0] = t0.x; pv[1] = t0.y; pv[2]  = t0.z; pv[3]  = t0.w;
        pv[4] = t1.x; pv[5] = t1.y; pv[6]  = t1.z; pv[7]  = t1.w;
        pv[8] = t2.x; pv[9] = t2.y; pv[10] = t2.z; pv[11] = t2.w;
    }

    const float* xb0 = x + ((size_t)(b * 64 + cg * 8) * 64 + h) * 768 + w * 12;
#pragma unroll
    for (int j = 0; j < 8; ++j) {
        const float* xp = xb0 + (size_t)j * 49152;
        float4 u0 = *(const float4*)(xp);
        float4 u1 = *(const float4*)(xp + 4);
        float4 u2 = *(const float4*)(xp + 8);
        float s = 0.f;
        s = fmaf(pv[0], u0.x, s);  s = fmaf(pv[1], u0.y, s);
        s = fmaf(pv[2], u0.z, s);  s = fmaf(pv[3], u0.w, s);
        s = fmaf(pv[4], u1.x, s);  s = fmaf(pv[5], u1.y, s);
        s = fmaf(pv[6], u1.z, s);  s = fmaf(pv[7], u1.w, s);
        s = fmaf(pv[8], u2.x, s);  s = fmaf(pv[9], u2.y, s);
        s = fmaf(pv[10], u2.z, s); s = fmaf(pv[11], u2.w, s);
        lds[w * 65 + cg * 8 + j] = s;
    }
    __syncthreads();

    const float* w1v = w1 + 128 * 64 + cg * 8 * 64;
    float acc[8];
#pragma unroll
    for (int j = 0; j < 8; ++j) acc[j] = b1[128 + cg * 8 + j];
    for (int c2 = 0; c2 < 64; ++c2) {
        const float xv = lds[w * 65 + c2];
#pragma unroll
        for (int j = 0; j < 8; ++j)
            acc[j] = fmaf(w1v[j * 64 + c2], xv, acc[j]);
    }

#pragma unroll
    for (int j = 0; j < 8; ++j) {
        const int co = cg * 8 + j;
        float4 f; f.x = acc[j]; f.y = acc[j]; f.z = acc[j]; f.w = acc[j];
        float* op = out + ((size_t)(b * 64 + co) * 4096 + h * 64 + w) * 12;
        *(float4*)(op)     = f;
        *(float4*)(op + 4) = f;
        *(float4*)(op + 8) = f;
    }
}

// ---------------------------------------------------------------------------
extern "C" void kernel_launch(void* const* d_in, const int* in_sizes, int n_in,
                              void* d_out, int out_size, void* d_ws, size_t ws_size,
                              hipStream_t stream) {
    const float* x  = (const float*)d_in[0];
    const float* w1 = (const float*)d_in[1];
    const float* b1 = (const float*)d_in[2];
    const float* w2 = (const float*)d_in[3];
    // d_in[4] = b2: constant across the softmax axis -> cancels, unused.

    float* outp = (float*)d_out;
    float* y    = outp + Y_OFF;      // 39.3 MB tap planes (scratch in d_out)
    float* p    = (float*)d_ws;      // 1.57 MB

    // weff: prefer d_ws (physically disjoint from y -> clean no-alias
    // provenance for the uniform weight loads); fall back to d_out scratch.
    const bool ws_fits = ws_size >= (size_t)(WS_WEFF_OFF + 1600) * sizeof(float);
    float* weff = ws_fits ? (p + WS_WEFF_OFF) : (outp + WEFF_OFF);

    hipLaunchKernelGGL(k_prep,   dim3(7),    dim3(256), 0, stream, w1, w2, weff);
    hipLaunchKernelGGL(k_tap,    dim3(1536), dim3(256), 0, stream, x, weff, y);
    hipLaunchKernelGGL(k_gather, dim3(512),  dim3(256), 0, stream, y, p);
    hipLaunchKernelGGL(k_out,    dim3(512),  dim3(512), 0, stream, x, w1, b1, p, outp);
}

// Round 16
// 97.305 us; speedup vs baseline: 2.2372x; 1.0194x over previous
//
#include <hip/hip_runtime.h>
#include <hip/hip_bf16.h>

// Problem dims: x[b=8, c=64, h=64, w=64, t=12] fp32
// x float offsets: b*3145728 + c*49152 + h*768 + w*12 + t
//
// Scratch inside d_out (floats), consumed before k_out overwrites d_out:
//   [4096, 4096+5*393216) : u[dh][m*12+t]  (5 planes, 7.9 MB — L2-resident)
#define U_OFF    4096
#define U_PLANE  393216   // floats per dh plane
// d_ws: p[m*12+t] (1.57 MB) + weff[c*25+tap] at float offset 393216
#define WS_WEFF_OFF 393216
#define WEFF_FALLBACK_OFF 0   // in d_out if ws too small

// ---------------------------------------------------------------------------
// K1: fold 1x1-conv (key half of w1) into the 5x5 conv weights.
__global__ __launch_bounds__(256) void k_prep(const float* __restrict__ w1,
                                              const float* __restrict__ w2,
                                              float* __restrict__ wdst) {
    int idx = blockIdx.x * 256 + threadIdx.x;
    if (idx >= 64 * 25) return;
    int cp = idx / 25, tap = idx % 25;
    float s = 0.f;
    for (int c = 0; c < 64; ++c)
        s = fmaf(w2[(64 + c) * 25 + tap], w1[(64 + c) * 64 + cp], s);
    wdst[cp * 25 + tap] = s;
}

// ---------------------------------------------------------------------------
// K2a (k_tap, dh-factored): u[dh][m,t] = sum_c sum_dw Weff[c,dh,dw] *
// x[c,h,w+dw-2,t]  (w-shift zero-padded). The dw-shifted loads are +-12/24
// floats from the center -> same cache lines the wave already reads (L1-hit).
// Intermediate shrinks 25 planes -> 5 (39.3 -> 7.9 MB, L2-resident).
// Thread per (m,t), 1536x256 = 24 waves/CU; acc = 5 scalars (~45 VGPR);
// c-loop in 4-channel batches (20 same-line loads outstanding).
__global__ __launch_bounds__(256) void k_tap(const float* __restrict__ x,
                                             const float* __restrict__ weff,
                                             float* __restrict__ u) {
    const int gid = blockIdx.x * 256 + threadIdx.x;   // 0..393215 = m*12+t
    const int m   = gid / 12;
    const int t   = gid - m * 12;
    const int w   = m & 63;
    const int h   = (m >> 6) & 63;
    const int b   = m >> 12;

    const float* xp = x + (size_t)b * 3145728 + h * 768 + w * 12 + t;

    // edge predicates + clamped offsets (no OOB addresses formed)
    const bool ok0 = (w >= 2), ok1 = (w >= 1), ok3 = (w <= 62), ok4 = (w <= 61);
    const int  o0 = ok0 ? -24 : 0, o1 = ok1 ? -12 : 0;
    const int  o3 = ok3 ?  12 : 0, o4 = ok4 ?  24 : 0;

    float u0 = 0.f, u1 = 0.f, u2 = 0.f, u3 = 0.f, u4 = 0.f;

    for (int cb = 0; cb < 16; ++cb) {
        float xv[4][5];
#pragma unroll
        for (int j = 0; j < 4; ++j) {
            const float* base = xp + (size_t)(cb * 4 + j) * 49152;
            float v0 = base[o0], v1 = base[o1], v2 = base[0];
            float v3 = base[o3], v4 = base[o4];
            xv[j][0] = ok0 ? v0 : 0.f;
            xv[j][1] = ok1 ? v1 : 0.f;
            xv[j][2] = v2;
            xv[j][3] = ok3 ? v3 : 0.f;
            xv[j][4] = ok4 ? v4 : 0.f;
        }
#pragma unroll
        for (int j = 0; j < 4; ++j) {
            const float* wg = weff + (cb * 4 + j) * 25;   // wave-uniform -> s_load
#pragma unroll
            for (int dw = 0; dw < 5; ++dw) {
                const float v = xv[j][dw];
                u0 = fmaf(wg[0 * 5 + dw], v, u0);
                u1 = fmaf(wg[1 * 5 + dw], v, u1);
                u2 = fmaf(wg[2 * 5 + dw], v, u2);
                u3 = fmaf(wg[3 * 5 + dw], v, u3);
                u4 = fmaf(wg[4 * 5 + dw], v, u4);
            }
        }
    }

    u[(size_t)0 * U_PLANE + gid] = u0;
    u[(size_t)1 * U_PLANE + gid] = u1;
    u[(size_t)2 * U_PLANE + gid] = u2;
    u[(size_t)3 * U_PLANE + gid] = u3;
    u[(size_t)4 * U_PLANE + gid] = u4;
}

// ---------------------------------------------------------------------------
// K2b (k_gather, 5-plane): A_k[m,t] = sum_dh u[dh][b, h+dh-2, w, t] (OOB dh
// skipped == zero-pad), softmax over t, write p. u is L2-resident (7.9 MB).
// Lane-quad per m: q=0..2 own t-quads, lane 3 mirrors lane 2.
__global__ __launch_bounds__(256) void k_gather(const float* __restrict__ u,
                                                float* __restrict__ p) {
    const int tid  = threadIdx.x;
    const int m    = blockIdx.x * 64 + (tid >> 2);   // 0..32767
    const int q    = tid & 3;
    const int qq   = (q == 3) ? 2 : q;
    const int w    = m & 63;
    const int h    = (m >> 6) & 63;
    const int b    = m >> 12;

    float4 a; a.x = 0.f; a.y = 0.f; a.z = 0.f; a.w = 0.f;

#pragma unroll
    for (int dh = 0; dh < 5; ++dh) {
        const int hh = h + dh - 2;
        if ((unsigned)hh >= 64u) continue;           // block-uniform skip
        const float* up = u + (size_t)dh * U_PLANE
                            + (size_t)(((b * 64 + hh) * 64 + w)) * 12 + qq * 4;
        float4 v = *(const float4*)(up);
        a.x += v.x; a.y += v.y; a.z += v.z; a.w += v.w;
    }

    float mx = fmaxf(fmaxf(a.x, a.y), fmaxf(a.z, a.w));
    mx = fmaxf(mx, __shfl_xor(mx, 1, 4));
    mx = fmaxf(mx, __shfl_xor(mx, 2, 4));

    float e0 = __expf(a.x - mx), e1 = __expf(a.y - mx);
    float e2 = __expf(a.z - mx), e3 = __expf(a.w - mx);
    const float s4 = e0 + e1 + e2 + e3;
    const float s0 = __shfl(s4, 0, 4);
    const float s1 = __shfl(s4, 1, 4);
    const float s2 = __shfl(s4, 2, 4);
    const float inv = 1.f / (s0 + s1 + s2);

    if (q < 3) {
        float4 o; o.x = e0 * inv; o.y = e1 * inv; o.z = e2 * inv; o.w = e3 * inv;
        *(float4*)(p + (size_t)m * 12 + q * 4) = o;
    }
}

// ---------------------------------------------------------------------------
// K4: out[b,c,h,w,s] = W1v · (sum_t p_t * x[:,t]) + b1v, broadcast over s.
// One block per (b,h): 512 threads = 64 w-lanes * 8 channel-groups.
// Proven ~34 us (near its 200MB roofline).
__global__ __launch_bounds__(512) void k_out(const float* __restrict__ x,
                                             const float* __restrict__ w1,
                                             const float* __restrict__ b1,
                                             const float* __restrict__ p,
                                             float* __restrict__ out) {
    __shared__ float lds[64 * 65];   // [w][c], padded -> conflict-free

    const int b  = blockIdx.x >> 6;
    const int h  = blockIdx.x & 63;
    const int w  = threadIdx.x & 63;
    const int cg = threadIdx.x >> 6;     // 0..7

    const float* pp = p + (size_t)((b * 64 + h) * 64 + w) * 12;
    float pv[12];
    {
        float4 t0 = *(const float4*)(pp);
        float4 t1 = *(const float4*)(pp + 4);
        float4 t2 = *(const float4*)(pp + 8);
        pv[0] = t0.x; pv[1] = t0.y; pv[2]  = t0.z; pv[3]  = t0.w;
        pv[4] = t1.x; pv[5] = t1.y; pv[6]  = t1.z; pv[7]  = t1.w;
        pv[8] = t2.x; pv[9] = t2.y; pv[10] = t2.z; pv[11] = t2.w;
    }

    const float* xb0 = x + ((size_t)(b * 64 + cg * 8) * 64 + h) * 768 + w * 12;
#pragma unroll
    for (int j = 0; j < 8; ++j) {
        const float* xp = xb0 + (size_t)j * 49152;
        float4 u0 = *(const float4*)(xp);
        float4 u1 = *(const float4*)(xp + 4);
        float4 u2 = *(const float4*)(xp + 8);
        float s = 0.f;
        s = fmaf(pv[0], u0.x, s);  s = fmaf(pv[1], u0.y, s);
        s = fmaf(pv[2], u0.z, s);  s = fmaf(pv[3], u0.w, s);
        s = fmaf(pv[4], u1.x, s);  s = fmaf(pv[5], u1.y, s);
        s = fmaf(pv[6], u1.z, s);  s = fmaf(pv[7], u1.w, s);
        s = fmaf(pv[8], u2.x, s);  s = fmaf(pv[9], u2.y, s);
        s = fmaf(pv[10], u2.z, s); s = fmaf(pv[11], u2.w, s);
        lds[w * 65 + cg * 8 + j] = s;
    }
    __syncthreads();

    const float* w1v = w1 + 128 * 64 + cg * 8 * 64;
    float acc[8];
#pragma unroll
    for (int j = 0; j < 8; ++j) acc[j] = b1[128 + cg * 8 + j];
    for (int c2 = 0; c2 < 64; ++c2) {
        const float xv = lds[w * 65 + c2];
#pragma unroll
        for (int j = 0; j < 8; ++j)
            acc[j] = fmaf(w1v[j * 64 + c2], xv, acc[j]);
    }

#pragma unroll
    for (int j = 0; j < 8; ++j) {
        const int co = cg * 8 + j;
        float4 f; f.x = acc[j]; f.y = acc[j]; f.z = acc[j]; f.w = acc[j];
        float* op = out + ((size_t)(b * 64 + co) * 4096 + h * 64 + w) * 12;
        *(float4*)(op)     = f;
        *(float4*)(op + 4) = f;
        *(float4*)(op + 8) = f;
    }
}

// ---------------------------------------------------------------------------
extern "C" void kernel_launch(void* const* d_in, const int* in_sizes, int n_in,
                              void* d_out, int out_size, void* d_ws, size_t ws_size,
                              hipStream_t stream) {
    const float* x  = (const float*)d_in[0];
    const float* w1 = (const float*)d_in[1];
    const float* b1 = (const float*)d_in[2];
    const float* w2 = (const float*)d_in[3];
    // d_in[4] = b2: constant across the softmax axis -> cancels, unused.

    float* outp = (float*)d_out;
    float* u    = outp + U_OFF;      // 7.9 MB dh-planes (scratch in d_out)
    float* p    = (float*)d_ws;      // 1.57 MB

    const bool ws_fits = ws_size >= (size_t)(WS_WEFF_OFF + 1600) * sizeof(float);
    float* weff = ws_fits ? (p + WS_WEFF_OFF) : (outp + WEFF_FALLBACK_OFF);

    hipLaunchKernelGGL(k_prep,   dim3(7),    dim3(256), 0, stream, w1, w2, weff);
    hipLaunchKernelGGL(k_tap,    dim3(1536), dim3(256), 0, stream, x, weff, u);
    hipLaunchKernelGGL(k_gather, dim3(512),  dim3(256), 0, stream, u, p);
    hipLaunchKernelGGL(k_out,    dim3(512),  dim3(512), 0, stream, x, w1, b1, p, outp);
}